// Round 1
// baseline (2012.080 us; speedup 1.0000x reference)
//
#include <hip/hip_runtime.h>
#include <hip/hip_bf16.h>

typedef __hip_bfloat16 bf16;
typedef __hip_bfloat162 bf162;

#define B_ 8
#define N_ 1024
#define M_ 1024
#define C_ 768
#define H_ 12
#define D_ 64
#define TILE 16
#define SROWS 18

__device__ __forceinline__ float bf2f(bf16 v){ return __bfloat162float(v); }
__device__ __forceinline__ bf16 f2bf(float v){ return __float2bfloat16(v); }

// ---------------- GEMM: A[8192 x 768] @ W[768 x ncols] ----------------
// mode 0: A=x (f32),   W=Wq  (ldw 768),  out -> Qb[b,h,n,d] bf16
// mode 1: A=ctx (f32), W=Wkv (ldw 1536), out -> Kb/Vb[b,h,m,d] bf16
// mode 2: A=midb(bf16),W=Wp  (ldw 768),  +bp, out -> outf[g,c] f32
__global__ __launch_bounds__(256)
void gemm_proj(const float* __restrict__ Af, const bf16* __restrict__ Ab,
               const float* __restrict__ W, int ldw,
               const float* __restrict__ bias,
               float* __restrict__ outf, bf16* __restrict__ outQ,
               bf16* __restrict__ outK, bf16* __restrict__ outV, int mode)
{
  __shared__ float As[16][129];   // [k][row], padded
  __shared__ float Bs[16][132];   // [k][col], padded (stride mult of 4 for float4)
  const int t = threadIdx.x;
  const int row0 = blockIdx.y * 128;
  const int c0 = blockIdx.x * 128;
  const int tx = t & 15, ty = t >> 4;

  float acc[8][8];
#pragma unroll
  for (int i=0;i<8;i++)
#pragma unroll
    for (int j=0;j<8;j++) acc[i][j]=0.f;

  const int lr  = t >> 1;          // A-load row 0..127
  const int lkq = (t & 1) * 8;     // A-load k offset {0,8}
  const int lkk = t >> 4;          // B-load k 0..15
  const int lc8 = (t & 15) * 8;    // B-load col offset

  for (int k0 = 0; k0 < C_; k0 += 16) {
    if (mode == 2) {
      const bf16* ap = Ab + (size_t)(row0+lr)*C_ + k0 + lkq;
      union { uint4 u; bf162 h[4]; } cv;
      cv.u = *reinterpret_cast<const uint4*>(ap);
#pragma unroll
      for (int q=0;q<4;q++){
        float2 f = __bfloat1622float2(cv.h[q]);
        As[lkq+2*q][lr]   = f.x;
        As[lkq+2*q+1][lr] = f.y;
      }
    } else {
      const float* ap = Af + (size_t)(row0+lr)*C_ + k0 + lkq;
      float4 a0 = *reinterpret_cast<const float4*>(ap);
      float4 a1 = *reinterpret_cast<const float4*>(ap+4);
      As[lkq+0][lr]=a0.x; As[lkq+1][lr]=a0.y; As[lkq+2][lr]=a0.z; As[lkq+3][lr]=a0.w;
      As[lkq+4][lr]=a1.x; As[lkq+5][lr]=a1.y; As[lkq+6][lr]=a1.z; As[lkq+7][lr]=a1.w;
    }
    {
      const float* wp = W + (size_t)(k0+lkk)*ldw + c0 + lc8;
      float4 b0 = *reinterpret_cast<const float4*>(wp);
      float4 b1 = *reinterpret_cast<const float4*>(wp+4);
      *reinterpret_cast<float4*>(&Bs[lkk][lc8])   = b0;
      *reinterpret_cast<float4*>(&Bs[lkk][lc8+4]) = b1;
    }
    __syncthreads();
#pragma unroll
    for (int kk=0;kk<16;kk++){
      float a[8];
#pragma unroll
      for (int i=0;i<8;i++) a[i] = As[kk][ty*8+i];
      float4 b0 = *reinterpret_cast<const float4*>(&Bs[kk][tx*8]);
      float4 b1 = *reinterpret_cast<const float4*>(&Bs[kk][tx*8+4]);
      float b[8] = {b0.x,b0.y,b0.z,b0.w,b1.x,b1.y,b1.z,b1.w};
#pragma unroll
      for (int i=0;i<8;i++)
#pragma unroll
        for (int j=0;j<8;j++)
          acc[i][j] = fmaf(a[i], b[j], acc[i][j]);
    }
    __syncthreads();
  }

  if (mode == 0) {
#pragma unroll
    for (int i=0;i<8;i++){
      int g = row0 + ty*8 + i;
      int b = g >> 10, n = g & 1023;
#pragma unroll
      for (int j=0;j<8;j+=2){
        int c = c0 + tx*8 + j;
        int h = c >> 6, dd = c & 63;
        size_t off = ((((size_t)b*H_ + h)*N_ + n)<<6) + dd;
        bf162 pr; pr.x = f2bf(acc[i][j]); pr.y = f2bf(acc[i][j+1]);
        *reinterpret_cast<bf162*>(&outQ[off]) = pr;
      }
    }
  } else if (mode == 1) {
#pragma unroll
    for (int i=0;i<8;i++){
      int g = row0 + ty*8 + i;
      int b = g >> 10, m = g & 1023;
#pragma unroll
      for (int j=0;j<8;j+=2){
        int c = c0 + tx*8 + j;
        bf16* dst = (c >= 768) ? outV : outK;
        int c7 = (c >= 768) ? (c - 768) : c;
        int h = c7 >> 6, dd = c7 & 63;
        size_t off = ((((size_t)b*H_ + h)*M_ + m)<<6) + dd;
        bf162 pr; pr.x = f2bf(acc[i][j]); pr.y = f2bf(acc[i][j+1]);
        *reinterpret_cast<bf162*>(&dst[off]) = pr;
      }
    }
  } else {
#pragma unroll
    for (int i=0;i<8;i++){
      int g = row0 + ty*8 + i;
      float* op = outf + (size_t)g*C_ + c0 + tx*8;
      const float* bpp = bias + c0 + tx*8;
      float4 o0 = make_float4(acc[i][0]+bpp[0], acc[i][1]+bpp[1],
                              acc[i][2]+bpp[2], acc[i][3]+bpp[3]);
      float4 o1 = make_float4(acc[i][4]+bpp[4], acc[i][5]+bpp[5],
                              acc[i][6]+bpp[6], acc[i][7]+bpp[7]);
      *reinterpret_cast<float4*>(op)   = o0;
      *reinterpret_cast<float4*>(op+4) = o1;
    }
  }
}

// -------- fused attention: scores -> softmax -> 3x3 depthwise conv -> PV ----
// one workgroup per (bh, 16-row query tile); softmax rows incl. 2 halo rows.
__global__ __launch_bounds__(512)
void attn_fused(const bf16* __restrict__ Qb, const bf16* __restrict__ Kb,
                const bf16* __restrict__ Vb,
                const float* __restrict__ conv_w, const float* __restrict__ conv_b,
                bf16* __restrict__ midb)
{
  __shared__ float qs[SROWS][D_];        // 4.5 KB
  __shared__ float sm[SROWS][M_];        // 72 KB  (softmax rows, full length)
  __shared__ float stage[64*260];        // 65 KB  (K chunk transposed / V chunk)
  __shared__ float ca[TILE][129];        // 8 KB   (conv'd attention chunk)

  const int t = threadIdx.x;
  const int tile = blockIdx.x;
  const int bh = blockIdx.y;
  const int b = bh / H_;
  const int h = bh - b*H_;
  const int n0 = tile * TILE;
  const size_t qbase = ((size_t)bh * N_) << 6;
  const size_t kbase = ((size_t)bh * M_) << 6;

  float w[9];
#pragma unroll
  for (int q=0;q<9;q++) w[q] = conv_w[h*9+q];
  const float cb = conv_b[h];

  // stage Q rows (incl. halo; out-of-range -> 0)
  for (int idx = t; idx < SROWS*D_; idx += 512){
    int r = idx >> 6, dd = idx & 63;
    int grow = n0 - 1 + r;
    float qv = 0.f;
    if (grow >= 0 && grow < N_) qv = bf2f(Qb[qbase + (((size_t)grow)<<6) + dd]);
    qs[r][dd] = qv;
  }

  // Phase A: scores. chunk 256 keys; ksT = stage[dd][mm] stride 260.
  const int aty = t >> 6;       // 0..7  (row group of 3; groups 6,7 idle)
  const int atx = t & 63;       // 0..63 (4 keys each)
  for (int mc = 0; mc < M_; mc += 256) {
    __syncthreads();
    for (int idx = t; idx < 64*128; idx += 512){
      int dd = (idx & 31) * 2;
      int mm = idx >> 5;
      bf162 kv = *reinterpret_cast<const bf162*>(&Kb[kbase + (((size_t)(mc+mm))<<6) + dd]);
      float2 f = __bfloat1622float2(kv);
      stage[dd*260 + mm]     = f.x;
      stage[(dd+1)*260 + mm] = f.y;
    }
    __syncthreads();
    if (aty < 6) {
      float s0[4]={0,0,0,0}, s1[4]={0,0,0,0}, s2[4]={0,0,0,0};
      const int r0 = aty*3;
#pragma unroll
      for (int dd=0; dd<64; dd++){
        float q0 = qs[r0+0][dd], q1 = qs[r0+1][dd], q2 = qs[r0+2][dd];
        float4 k4 = *reinterpret_cast<const float4*>(&stage[dd*260 + 4*atx]);
        s0[0]=fmaf(q0,k4.x,s0[0]); s0[1]=fmaf(q0,k4.y,s0[1]); s0[2]=fmaf(q0,k4.z,s0[2]); s0[3]=fmaf(q0,k4.w,s0[3]);
        s1[0]=fmaf(q1,k4.x,s1[0]); s1[1]=fmaf(q1,k4.y,s1[1]); s1[2]=fmaf(q1,k4.z,s1[2]); s1[3]=fmaf(q1,k4.w,s1[3]);
        s2[0]=fmaf(q2,k4.x,s2[0]); s2[1]=fmaf(q2,k4.y,s2[1]); s2[2]=fmaf(q2,k4.z,s2[2]); s2[3]=fmaf(q2,k4.w,s2[3]);
      }
      const float scl = 0.125f;
      *reinterpret_cast<float4*>(&sm[r0+0][mc+4*atx]) = make_float4(s0[0]*scl,s0[1]*scl,s0[2]*scl,s0[3]*scl);
      *reinterpret_cast<float4*>(&sm[r0+1][mc+4*atx]) = make_float4(s1[0]*scl,s1[1]*scl,s1[2]*scl,s1[3]*scl);
      *reinterpret_cast<float4*>(&sm[r0+2][mc+4*atx]) = make_float4(s2[0]*scl,s2[1]*scl,s2[2]*scl,s2[3]*scl);
    }
  }
  __syncthreads();

  // Phase B: per-row softmax (one wave per row). Invalid halo rows -> zeros.
  {
    const int wv = t >> 6, lane = t & 63;
    for (int r = wv; r < SROWS; r += 8){
      int grow = n0 - 1 + r;
      if (grow < 0 || grow >= N_){
        for (int kk=0;kk<16;kk++) sm[r][lane + (kk<<6)] = 0.f;
        continue;
      }
      float vals[16];
      float mx = -1e30f;
#pragma unroll
      for (int kk=0;kk<16;kk++){ vals[kk] = sm[r][lane+(kk<<6)]; mx = fmaxf(mx, vals[kk]); }
#pragma unroll
      for (int off=32; off; off>>=1) mx = fmaxf(mx, __shfl_xor(mx, off));
      float s = 0.f;
#pragma unroll
      for (int kk=0;kk<16;kk++){ float p = __expf(vals[kk]-mx); vals[kk] = p; s += p; }
#pragma unroll
      for (int off=32; off; off>>=1) s += __shfl_xor(s, off);
      float inv = 1.f/s;
#pragma unroll
      for (int kk=0;kk<16;kk++) sm[r][lane+(kk<<6)] = vals[kk]*inv;
    }
  }

  // Phase C: conv into ca chunk, then PV against LDS-staged V chunk.
  const int prr = t >> 5;     // output row 0..15
  const int dg  = t & 31;     // d pair 0..31
  float acc0 = 0.f, acc1 = 0.f;
  for (int mc = 0; mc < M_; mc += 128) {
    __syncthreads();
    for (int idx = t; idx < 128*32; idx += 512){
      int dd = (idx & 31)*2;
      int mm = idx >> 5;
      bf162 vv = *reinterpret_cast<const bf162*>(&Vb[kbase + (((size_t)(mc+mm))<<6) + dd]);
      *reinterpret_cast<float2*>(&stage[mm*68 + dd]) = __bfloat1622float2(vv);
    }
    for (int e = t; e < TILE*128; e += 512){
      int r = e >> 7, mm = e & 127;
      int gm = mc + mm;
      float sacc = cb;
#pragma unroll
      for (int i=0;i<3;i++){
#pragma unroll
        for (int jj=0;jj<3;jj++){
          int ccc = gm + jj - 1;
          float v = ((unsigned)ccc < (unsigned)M_) ? sm[r+i][ccc] : 0.f;
          sacc = fmaf(w[i*3+jj], v, sacc);
        }
      }
      ca[r][mm] = sacc;
    }
    __syncthreads();
#pragma unroll 4
    for (int mm=0; mm<128; mm++){
      float cav = ca[prr][mm];
      float2 vv = *reinterpret_cast<const float2*>(&stage[mm*68 + 2*dg]);
      acc0 = fmaf(cav, vv.x, acc0);
      acc1 = fmaf(cav, vv.y, acc1);
    }
  }

  {
    int n = n0 + prr;
    size_t off = ((size_t)b*N_ + n)*C_ + h*D_ + 2*dg;
    bf162 o; o.x = f2bf(acc0); o.y = f2bf(acc1);
    *reinterpret_cast<bf162*>(&midb[off]) = o;
  }
}

extern "C" void kernel_launch(void* const* d_in, const int* in_sizes, int n_in,
                              void* d_out, int out_size, void* d_ws, size_t ws_size,
                              hipStream_t stream) {
  const float* x     = (const float*)d_in[0];
  const float* ctx   = (const float*)d_in[1];
  const float* Wq    = (const float*)d_in[2];
  const float* Wkv   = (const float*)d_in[3];
  const float* convw = (const float*)d_in[4];
  const float* convb = (const float*)d_in[5];
  const float* Wp    = (const float*)d_in[6];
  const float* bp    = (const float*)d_in[7];
  float* out = (float*)d_out;

  char* ws = (char*)d_ws;
  bf16* Qb   = (bf16*)(ws);                 // 12582912 B
  bf16* Kb   = (bf16*)(ws + 12582912);
  bf16* Vb   = (bf16*)(ws + 25165824);
  bf16* midb = (bf16*)(ws + 37748736);      // total 50331648 B

  gemm_proj<<<dim3(6,64),  dim3(256), 0, stream>>>(x,   nullptr, Wq,  768,  nullptr, nullptr, Qb, nullptr, nullptr, 0);
  gemm_proj<<<dim3(12,64), dim3(256), 0, stream>>>(ctx, nullptr, Wkv, 1536, nullptr, nullptr, nullptr, Kb, Vb, 1);
  attn_fused<<<dim3(64,96), dim3(512), 0, stream>>>(Qb, Kb, Vb, convw, convb, midb);
  gemm_proj<<<dim3(6,64),  dim3(256), 0, stream>>>(nullptr, midb, Wp, 768, bp, out, nullptr, nullptr, nullptr, 2);
}

// Round 2
// 724.994 us; speedup vs baseline: 2.7753x; 2.7753x over previous
//
#include <hip/hip_runtime.h>
#include <hip/hip_bf16.h>

typedef __hip_bfloat16 bf16;
typedef __hip_bfloat162 bf162;

#define B_ 8
#define N_ 1024
#define M_ 1024
#define C_ 768
#define H_ 12
#define D_ 64
#define TOUT 30
#define NT 35   // ceil(1024/30)

typedef __attribute__((ext_vector_type(8))) short short8v;
typedef __attribute__((ext_vector_type(4))) float f32x4;

__device__ __forceinline__ float bf2f(bf16 v){ return __bfloat162float(v); }
__device__ __forceinline__ bf16 f2bf(float v){ return __float2bfloat16(v); }

// ---------------- GEMM: A[8192 x 768] @ W[768 x ncols] ----------------
// mode 0: A=x (f32),   W=Wq  (ldw 768),  out -> Qb[b,h,n,d] bf16
// mode 1: A=ctx (f32), W=Wkv (ldw 1536), out -> Kb[b,h,m,d] / Vt[b,h,d,m] bf16
// mode 2: A=midb(bf16),W=Wp  (ldw 768),  +bp, out -> outf[g,c] f32
__global__ __launch_bounds__(256)
void gemm_proj(const float* __restrict__ Af, const bf16* __restrict__ Ab,
               const float* __restrict__ W, int ldw,
               const float* __restrict__ bias,
               float* __restrict__ outf, bf16* __restrict__ outQ,
               bf16* __restrict__ outK, bf16* __restrict__ outV, int mode)
{
  __shared__ float As[16][129];
  __shared__ float Bs[16][132];
  const int t = threadIdx.x;
  const int row0 = blockIdx.y * 128;
  const int c0 = blockIdx.x * 128;
  const int tx = t & 15, ty = t >> 4;

  float acc[8][8];
#pragma unroll
  for (int i=0;i<8;i++)
#pragma unroll
    for (int j=0;j<8;j++) acc[i][j]=0.f;

  const int lr  = t >> 1;
  const int lkq = (t & 1) * 8;
  const int lkk = t >> 4;
  const int lc8 = (t & 15) * 8;

  for (int k0 = 0; k0 < C_; k0 += 16) {
    if (mode == 2) {
      const bf16* ap = Ab + (size_t)(row0+lr)*C_ + k0 + lkq;
      union { uint4 u; bf162 h[4]; } cv;
      cv.u = *reinterpret_cast<const uint4*>(ap);
#pragma unroll
      for (int q=0;q<4;q++){
        float2 f = __bfloat1622float2(cv.h[q]);
        As[lkq+2*q][lr]   = f.x;
        As[lkq+2*q+1][lr] = f.y;
      }
    } else {
      const float* ap = Af + (size_t)(row0+lr)*C_ + k0 + lkq;
      float4 a0 = *reinterpret_cast<const float4*>(ap);
      float4 a1 = *reinterpret_cast<const float4*>(ap+4);
      As[lkq+0][lr]=a0.x; As[lkq+1][lr]=a0.y; As[lkq+2][lr]=a0.z; As[lkq+3][lr]=a0.w;
      As[lkq+4][lr]=a1.x; As[lkq+5][lr]=a1.y; As[lkq+6][lr]=a1.z; As[lkq+7][lr]=a1.w;
    }
    {
      const float* wp = W + (size_t)(k0+lkk)*ldw + c0 + lc8;
      float4 b0 = *reinterpret_cast<const float4*>(wp);
      float4 b1 = *reinterpret_cast<const float4*>(wp+4);
      *reinterpret_cast<float4*>(&Bs[lkk][lc8])   = b0;
      *reinterpret_cast<float4*>(&Bs[lkk][lc8+4]) = b1;
    }
    __syncthreads();
#pragma unroll
    for (int kk=0;kk<16;kk++){
      float a[8];
#pragma unroll
      for (int i=0;i<8;i++) a[i] = As[kk][ty*8+i];
      float4 b0 = *reinterpret_cast<const float4*>(&Bs[kk][tx*8]);
      float4 b1 = *reinterpret_cast<const float4*>(&Bs[kk][tx*8+4]);
      float b[8] = {b0.x,b0.y,b0.z,b0.w,b1.x,b1.y,b1.z,b1.w};
#pragma unroll
      for (int i=0;i<8;i++)
#pragma unroll
        for (int j=0;j<8;j++)
          acc[i][j] = fmaf(a[i], b[j], acc[i][j]);
    }
    __syncthreads();
  }

  if (mode == 0) {
#pragma unroll
    for (int i=0;i<8;i++){
      int g = row0 + ty*8 + i;
      int b = g >> 10, n = g & 1023;
#pragma unroll
      for (int j=0;j<8;j+=2){
        int c = c0 + tx*8 + j;
        int h = c >> 6, dd = c & 63;
        size_t off = ((((size_t)b*H_ + h)*N_ + n)<<6) + dd;
        bf162 pr; pr.x = f2bf(acc[i][j]); pr.y = f2bf(acc[i][j+1]);
        *reinterpret_cast<bf162*>(&outQ[off]) = pr;
      }
    }
  } else if (mode == 1) {
    if (c0 < 768) {
      // K half: layout [b,h,m,d]
#pragma unroll
      for (int i=0;i<8;i++){
        int g = row0 + ty*8 + i;
        int b = g >> 10, m = g & 1023;
#pragma unroll
        for (int j=0;j<8;j+=2){
          int c = c0 + tx*8 + j;
          int h = c >> 6, dd = c & 63;
          size_t off = ((((size_t)b*H_ + h)*M_ + m)<<6) + dd;
          bf162 pr; pr.x = f2bf(acc[i][j]); pr.y = f2bf(acc[i][j+1]);
          *reinterpret_cast<bf162*>(&outK[off]) = pr;
        }
      }
    } else {
      // V half: transposed layout Vt[b,h,d,m], 16B stores of 8 consecutive m
      int grow = row0 + ty*8;
      int b = grow >> 10, m0 = grow & 1023;
#pragma unroll
      for (int j=0;j<8;j++){
        int c7 = c0 - 768 + tx*8 + j;
        int hh = c7 >> 6, dd = c7 & 63;
        union { uint4 u; bf16 h[8]; } pk;
#pragma unroll
        for (int i=0;i<8;i++) pk.h[i] = f2bf(acc[i][j]);
        size_t off = (((size_t)b*H_ + hh)*D_ + dd)*(size_t)M_ + m0;
        *reinterpret_cast<uint4*>(&outV[off]) = pk.u;
      }
    }
  } else {
#pragma unroll
    for (int i=0;i<8;i++){
      int g = row0 + ty*8 + i;
      float* op = outf + (size_t)g*C_ + c0 + tx*8;
      const float* bpp = bias + c0 + tx*8;
      float4 o0 = make_float4(acc[i][0]+bpp[0], acc[i][1]+bpp[1],
                              acc[i][2]+bpp[2], acc[i][3]+bpp[3]);
      float4 o1 = make_float4(acc[i][4]+bpp[4], acc[i][5]+bpp[5],
                              acc[i][6]+bpp[6], acc[i][7]+bpp[7]);
      *reinterpret_cast<float4*>(op)   = o0;
      *reinterpret_cast<float4*>(op+4) = o1;
    }
  }
}

// -------- fused attention v2: MFMA scores -> reg softmax -> conv -> MFMA PV --
// 32 score rows per WG (n0-1 .. n0+30), 30 outputs. 8 waves (512 thr).
__global__ __launch_bounds__(512, 4)
void attn_fused(const bf16* __restrict__ Qb, const bf16* __restrict__ Kb,
                const bf16* __restrict__ Vt,
                const float* __restrict__ conv_w, const float* __restrict__ conv_b,
                bf16* __restrict__ midb)
{
  __shared__ bf16  smP[1024*34];     // P, column-major [m][r], ld=34 -> 68 KB
  __shared__ bf16  Acs[32*128];      // conv'd chunk, row-major swizzled, 8 KB
  __shared__ float red[2][8][32];    // cross-wave softmax reduce, 2 KB

  const int t = threadIdx.x;
  const int w = t >> 6, l = t & 63;
  const int lr = l & 15, g = l >> 4;

  // XCD-bijective swizzle: 3360 WGs -> 8 chunks of 420 (whole bh's per XCD)
  int L = blockIdx.x + blockIdx.y * NT;
  int L2 = (L & 7) * 420 + (L >> 3);
  const int bh = L2 / NT;
  const int tile = L2 - bh * NT;
  const int b = bh / H_, h = bh - b*H_;
  const int n0 = tile * TOUT;

  const bf16* Qp = Qb + (size_t)bh * (N_*D_);
  const bf16* Kp = Kb + (size_t)bh * (M_*D_);
  const bf16* Vp = Vt + (size_t)bh * (D_*M_);

  float wv[9];
#pragma unroll
  for (int q=0;q<9;q++) wv[q] = conv_w[h*9+q];
  const float cbv = conv_b[h];

  // ---- Q fragments (registers), halo rows zeroed ----
  short8v qf[2][2];
#pragma unroll
  for (int rt=0;rt<2;rt++){
    int n = n0 - 1 + rt*16 + lr;
    bool ok = (unsigned)n < (unsigned)N_;
#pragma unroll
    for (int kk=0;kk<2;kk++){
      if (ok) qf[rt][kk] = *reinterpret_cast<const short8v*>(Qp + (size_t)n*D_ + kk*32 + g*8);
      else    qf[rt][kk] = short8v{0,0,0,0,0,0,0,0};
    }
  }

  // ---- Phase A: scores S[32][1024] via MFMA; wave w owns cols (8i+w)*16 ----
  f32x4 acc[8][2];
#pragma unroll
  for (int i=0;i<8;i++)
#pragma unroll
    for (int rt=0;rt<2;rt++)
      acc[i][rt] = (f32x4){0.f,0.f,0.f,0.f};

#pragma unroll
  for (int i=0;i<8;i++){
    const int m0 = (i*8 + w)*16;
    const bf16* kp = Kp + (size_t)(m0 + lr)*D_ + g*8;
    short8v kf0 = *reinterpret_cast<const short8v*>(kp);
    short8v kf1 = *reinterpret_cast<const short8v*>(kp + 32);
    acc[i][0] = __builtin_amdgcn_mfma_f32_16x16x32_bf16(qf[0][0], kf0, acc[i][0], 0,0,0);
    acc[i][1] = __builtin_amdgcn_mfma_f32_16x16x32_bf16(qf[1][0], kf0, acc[i][1], 0,0,0);
    acc[i][0] = __builtin_amdgcn_mfma_f32_16x16x32_bf16(qf[0][1], kf1, acc[i][0], 0,0,0);
    acc[i][1] = __builtin_amdgcn_mfma_f32_16x16x32_bf16(qf[1][1], kf1, acc[i][1], 0,0,0);
  }

  // ---- softmax over rows (row = rt*16 + g*4 + q), scale folded into exp ----
  const float scale = 0.125f;
  float rmax[2][4], rsum[2][4];

#pragma unroll
  for (int rt=0;rt<2;rt++)
#pragma unroll
    for (int q=0;q<4;q++){
      float m = -1e30f;
#pragma unroll
      for (int i=0;i<8;i++) m = fmaxf(m, acc[i][rt][q]);
      m = fmaxf(m, __shfl_xor(m, 1));
      m = fmaxf(m, __shfl_xor(m, 2));
      m = fmaxf(m, __shfl_xor(m, 4));
      m = fmaxf(m, __shfl_xor(m, 8));
      rmax[rt][q] = m;
    }
  if (lr == 0){
#pragma unroll
    for (int rt=0;rt<2;rt++)
#pragma unroll
      for (int q=0;q<4;q++) red[0][w][rt*16+g*4+q] = rmax[rt][q];
  }
  __syncthreads();
#pragma unroll
  for (int rt=0;rt<2;rt++)
#pragma unroll
    for (int q=0;q<4;q++){
      int r = rt*16+g*4+q;
      float m = red[0][0][r];
#pragma unroll
      for (int ww=1;ww<8;ww++) m = fmaxf(m, red[0][ww][r]);
      rmax[rt][q] = m;
    }

#pragma unroll
  for (int rt=0;rt<2;rt++)
#pragma unroll
    for (int q=0;q<4;q++){
      float s = 0.f;
#pragma unroll
      for (int i=0;i<8;i++){
        float p = __expf((acc[i][rt][q] - rmax[rt][q]) * scale);
        acc[i][rt][q] = p;
        s += p;
      }
      s += __shfl_xor(s, 1);
      s += __shfl_xor(s, 2);
      s += __shfl_xor(s, 4);
      s += __shfl_xor(s, 8);
      rsum[rt][q] = s;
    }
  if (lr == 0){
#pragma unroll
    for (int rt=0;rt<2;rt++)
#pragma unroll
      for (int q=0;q<4;q++) red[1][w][rt*16+g*4+q] = rsum[rt][q];
  }
  __syncthreads();

  float rinv[2][4];
#pragma unroll
  for (int rt=0;rt<2;rt++)
#pragma unroll
    for (int q=0;q<4;q++){
      int r = rt*16+g*4+q;
      float s = red[1][0][r];
#pragma unroll
      for (int ww=1;ww<8;ww++) s += red[1][ww][r];
      int n = n0 - 1 + r;
      rinv[rt][q] = ((unsigned)n < (unsigned)N_) ? (1.0f / s) : 0.f;  // zero invalid rows
    }

  // ---- write normalized P (bf16) column-major into smP ----
#pragma unroll
  for (int i=0;i<8;i++){
    const int m = (i*8 + w)*16 + lr;
#pragma unroll
    for (int rt=0;rt<2;rt++){
      bf162* dp = reinterpret_cast<bf162*>(&smP[m*34 + rt*16 + g*4]);
      bf162 v0, v1;
      v0.x = f2bf(acc[i][rt][0] * rinv[rt][0]);
      v0.y = f2bf(acc[i][rt][1] * rinv[rt][1]);
      v1.x = f2bf(acc[i][rt][2] * rinv[rt][2]);
      v1.y = f2bf(acc[i][rt][3] * rinv[rt][3]);
      dp[0] = v0; dp[1] = v1;
    }
  }
  __syncthreads();

  // ---- conv + PV, chunks of 128 cols ----
  const int mm = t & 127, rb = t >> 7;       // conv: col-in-chunk, row block
  const int rtw = w >> 2, ctw = w & 3;       // PV: wave's (row-tile, d-tile)
  const int rrow = rtw*16 + lr;
  f32x4 apv = (f32x4){0.f,0.f,0.f,0.f};

  for (int mc = 0; mc < M_; mc += 128){
    // conv: Ac[r][mc+mm] for r = rb*8 .. rb*8+7 (rows 0,31 are discard-garbage)
    const int m = mc + mm;
    const int r0 = rb*8;
    float c0a[10], c1a[10], c2a[10];
#pragma unroll
    for (int q=0;q<10;q++){
      int rr = r0 - 1 + q;
      rr = rr < 0 ? 0 : (rr > 31 ? 31 : rr);
      c0a[q] = (m >= 1)      ? bf2f(smP[(m-1)*34 + rr]) : 0.f;
      c1a[q] =                 bf2f(smP[ m   *34 + rr]);
      c2a[q] = (m+1 < M_)    ? bf2f(smP[(m+1)*34 + rr]) : 0.f;
    }
#pragma unroll
    for (int q=0;q<8;q++){
      float v = cbv;
      v = fmaf(wv[0], c0a[q],   v); v = fmaf(wv[1], c1a[q],   v); v = fmaf(wv[2], c2a[q],   v);
      v = fmaf(wv[3], c0a[q+1], v); v = fmaf(wv[4], c1a[q+1], v); v = fmaf(wv[5], c2a[q+1], v);
      v = fmaf(wv[6], c0a[q+2], v); v = fmaf(wv[7], c1a[q+2], v); v = fmaf(wv[8], c2a[q+2], v);
      int r = r0 + q;
      Acs[r*128 + (mm ^ ((r & 7) << 3))] = f2bf(v);
    }
    __syncthreads();

    // PV: out[32][64] += Ac[32][128] @ V[128][64]
#pragma unroll
    for (int ks=0;ks<4;ks++){
      short8v af = *reinterpret_cast<const short8v*>(
          &Acs[rrow*128 + ((ks*32 + g*8) ^ ((rrow & 7) << 3))]);
      short8v bfv = *reinterpret_cast<const short8v*>(
          Vp + (size_t)(ctw*16 + lr)*M_ + mc + ks*32 + g*8);
      apv = __builtin_amdgcn_mfma_f32_16x16x32_bf16(af, bfv, apv, 0,0,0);
    }
    __syncthreads();
  }

  // ---- write outputs (rows 1..30 valid) ----
  const int dcol = ctw*16 + lr;
#pragma unroll
  for (int q=0;q<4;q++){
    int r = rtw*16 + g*4 + q;
    int n = n0 - 1 + r;
    if (r >= 1 && r <= 30 && n < N_){
      midb[((size_t)b*N_ + n)*C_ + h*D_ + dcol] = f2bf(apv[q]);
    }
  }
}

extern "C" void kernel_launch(void* const* d_in, const int* in_sizes, int n_in,
                              void* d_out, int out_size, void* d_ws, size_t ws_size,
                              hipStream_t stream) {
  const float* x     = (const float*)d_in[0];
  const float* ctx   = (const float*)d_in[1];
  const float* Wq    = (const float*)d_in[2];
  const float* Wkv   = (const float*)d_in[3];
  const float* convw = (const float*)d_in[4];
  const float* convb = (const float*)d_in[5];
  const float* Wp    = (const float*)d_in[6];
  const float* bp    = (const float*)d_in[7];
  float* out = (float*)d_out;

  char* ws = (char*)d_ws;
  bf16* Qb   = (bf16*)(ws);                 // 12582912 B
  bf16* Kb   = (bf16*)(ws + 12582912);
  bf16* Vt   = (bf16*)(ws + 25165824);      // transposed V [b,h,d,m]
  bf16* midb = (bf16*)(ws + 37748736);      // total 50331648 B

  gemm_proj<<<dim3(6,64),  dim3(256), 0, stream>>>(x,   nullptr, Wq,  768,  nullptr, nullptr, Qb, nullptr, nullptr, 0);
  gemm_proj<<<dim3(12,64), dim3(256), 0, stream>>>(ctx, nullptr, Wkv, 1536, nullptr, nullptr, nullptr, Kb, Vt, 1);
  attn_fused<<<dim3(NT,96), dim3(512), 0, stream>>>(Qb, Kb, Vt, convw, convb, midb);
  gemm_proj<<<dim3(6,64),  dim3(256), 0, stream>>>(nullptr, midb, Wp, 768, bp, out, nullptr, nullptr, nullptr, 2);
}

// Round 3
// 316.793 us; speedup vs baseline: 6.3514x; 2.2885x over previous
//
#include <hip/hip_runtime.h>
#include <hip/hip_bf16.h>

typedef __hip_bfloat16 bf16;
typedef __hip_bfloat162 bf162;

#define B_ 8
#define N_ 1024
#define M_ 1024
#define C_ 768
#define H_ 12
#define D_ 64
#define TOUT 30
#define NT 35   // ceil(1024/30)

typedef __attribute__((ext_vector_type(8))) short short8v;
typedef __attribute__((ext_vector_type(4))) float f32x4;

__device__ __forceinline__ float bf2f(bf16 v){ return __bfloat162float(v); }
__device__ __forceinline__ bf16 f2bf(float v){ return __float2bfloat16(v); }

__device__ __forceinline__ void gl_lds16(const bf16* g, bf16* l){
  __builtin_amdgcn_global_load_lds((const __attribute__((address_space(1))) unsigned*)g,
                                   (__attribute__((address_space(3))) unsigned*)l, 16, 0, 0);
}

// ---------------- prep: fp32 -> bf16 convert (8 elems/thread) ----------------
__global__ __launch_bounds__(256)
void cvt_bf16(const float* __restrict__ in, bf16* __restrict__ out, int n8){
  int i = blockIdx.x*256 + threadIdx.x;
  if (i < n8){
    const float4* ip = reinterpret_cast<const float4*>(in) + 2*(size_t)i;
    float4 a = ip[0], b = ip[1];
    union { uint4 u; bf16 h[8]; } pk;
    pk.h[0]=f2bf(a.x); pk.h[1]=f2bf(a.y); pk.h[2]=f2bf(a.z); pk.h[3]=f2bf(a.w);
    pk.h[4]=f2bf(b.x); pk.h[5]=f2bf(b.y); pk.h[6]=f2bf(b.z); pk.h[7]=f2bf(b.w);
    reinterpret_cast<uint4*>(out)[i] = pk.u;
  }
}

// ---------------- prep: W[K][N] f32 -> Wt[N][K] bf16 ----------------
__global__ __launch_bounds__(256)
void transpose_w(const float* __restrict__ W, bf16* __restrict__ Wt, int K, int N){
  __shared__ float tile[32][33];
  const int n0 = blockIdx.x*32, k0 = blockIdx.y*32;
  const int tx = threadIdx.x & 31, ty = threadIdx.x >> 5;
#pragma unroll
  for (int i=0;i<32;i+=8) tile[ty+i][tx] = W[(size_t)(k0+ty+i)*N + n0+tx];
  __syncthreads();
#pragma unroll
  for (int i=0;i<32;i+=8) Wt[(size_t)(n0+ty+i)*K + k0+tx] = f2bf(tile[tx][ty+i]);
}

// ---------------- bf16 MFMA GEMM: A[8192][K] @ Bt[N][K]^T ----------------
// mode 0: out -> Qb[b,h,n,d] bf16
// mode 1: cols<768 -> Kb[b,h,m,d]; cols>=768 -> Vt[b,h,d,m] (8B vec stores)
// mode 2: +bias -> outf fp32
__global__ __launch_bounds__(256)
void gemm_bf16(const bf16* __restrict__ A, const bf16* __restrict__ Bt, int K,
               int nbx, const float* __restrict__ bias,
               float* __restrict__ outf, bf16* __restrict__ outQ,
               bf16* __restrict__ outK, bf16* __restrict__ outV, int mode)
{
  __shared__ bf16 As[128*32];
  __shared__ bf16 Bs[128*32];

  // bijective XCD swizzle (nwg = 64*nbx, multiple of 8)
  const int nwg = 64*nbx, cpx = nwg >> 3;
  int bid = blockIdx.x;
  bid = (bid & 7)*cpx + (bid >> 3);
  const int rowb = bid / nbx, colb = bid - rowb*nbx;
  const int row0 = rowb*128, c0 = colb*128;

  const int t = threadIdx.x;
  const int w = t>>6, l = t&63, lr = l&15, g = l>>4;
  const int wr = w>>1, wc = w&1;

  const bf16* Ap = A + (size_t)row0*K;
  const bf16* Bp = Bt + (size_t)c0*K;
  const int srow = t>>2;
  const int schunk = (t&3)*8;

  f32x4 acc[4][4];
#pragma unroll
  for (int mi=0;mi<4;mi++)
#pragma unroll
    for (int ni=0;ni<4;ni++) acc[mi][ni] = (f32x4){0.f,0.f,0.f,0.f};

  for (int k0 = 0; k0 < K; k0 += 32){
    gl_lds16(Ap + (size_t)srow*K      + k0 + schunk, As + t*8);
    gl_lds16(Ap + (size_t)(srow+64)*K + k0 + schunk, As + 2048 + t*8);
    gl_lds16(Bp + (size_t)srow*K      + k0 + schunk, Bs + t*8);
    gl_lds16(Bp + (size_t)(srow+64)*K + k0 + schunk, Bs + 2048 + t*8);
    __syncthreads();

    short8v a[4], b[4];
#pragma unroll
    for (int mi=0;mi<4;mi++)
      a[mi] = *reinterpret_cast<const short8v*>(&As[(wr*64+mi*16+lr)*32 + g*8]);
#pragma unroll
    for (int ni=0;ni<4;ni++)
      b[ni] = *reinterpret_cast<const short8v*>(&Bs[(wc*64+ni*16+lr)*32 + g*8]);
#pragma unroll
    for (int mi=0;mi<4;mi++)
#pragma unroll
      for (int ni=0;ni<4;ni++)
        acc[mi][ni] = __builtin_amdgcn_mfma_f32_16x16x32_bf16(a[mi], b[ni], acc[mi][ni], 0,0,0);
    __syncthreads();
  }

  if (mode == 2){
    float bv[4];
#pragma unroll
    for (int ni=0;ni<4;ni++) bv[ni] = bias[c0 + wc*64 + ni*16 + lr];
#pragma unroll
    for (int mi=0;mi<4;mi++)
#pragma unroll
      for (int ni=0;ni<4;ni++){
        int c = c0 + wc*64 + ni*16 + lr;
#pragma unroll
        for (int q=0;q<4;q++){
          int grow = row0 + wr*64 + mi*16 + g*4 + q;
          outf[(size_t)grow*C_ + c] = acc[mi][ni][q] + bv[ni];
        }
      }
  } else if (mode == 0){
#pragma unroll
    for (int mi=0;mi<4;mi++)
#pragma unroll
      for (int ni=0;ni<4;ni++){
        int c = c0 + wc*64 + ni*16 + lr;
        int h = c >> 6, dd = c & 63;
#pragma unroll
        for (int q=0;q<4;q++){
          int grow = row0 + wr*64 + mi*16 + g*4 + q;
          int b = grow >> 10, n = grow & 1023;
          outQ[((((size_t)b*H_ + h)*N_ + n)<<6) + dd] = f2bf(acc[mi][ni][q]);
        }
      }
  } else {
#pragma unroll
    for (int mi=0;mi<4;mi++)
#pragma unroll
      for (int ni=0;ni<4;ni++){
        int c = c0 + wc*64 + ni*16 + lr;
        if (c < 768){
          int h = c >> 6, dd = c & 63;
#pragma unroll
          for (int q=0;q<4;q++){
            int grow = row0 + wr*64 + mi*16 + g*4 + q;
            int b = grow >> 10, m = grow & 1023;
            outK[((((size_t)b*H_ + h)*M_ + m)<<6) + dd] = f2bf(acc[mi][ni][q]);
          }
        } else {
          int cc = c - 768;
          int h = cc >> 6, dd = cc & 63;
          int grow = row0 + wr*64 + mi*16 + g*4;
          int b = grow >> 10, m = grow & 1023;
          union { ushort4 u; bf16 hh[4]; } pk;
#pragma unroll
          for (int q=0;q<4;q++) pk.hh[q] = f2bf(acc[mi][ni][q]);
          size_t off = (((size_t)b*H_ + h)*D_ + dd)*(size_t)M_ + m;
          *reinterpret_cast<ushort4*>(&outV[off]) = pk.u;
        }
      }
  }
}

// -------- fused attention: MFMA scores -> reg softmax -> conv -> MFMA PV --
__global__ __launch_bounds__(512, 4)
void attn_fused(const bf16* __restrict__ Qb, const bf16* __restrict__ Kb,
                const bf16* __restrict__ Vt,
                const float* __restrict__ conv_w, const float* __restrict__ conv_b,
                bf16* __restrict__ midb)
{
  __shared__ bf16  smP[1024*34];
  __shared__ bf16  Acs[32*128];
  __shared__ float red[2][8][32];

  const int t = threadIdx.x;
  const int w = t >> 6, l = t & 63;
  const int lr = l & 15, g = l >> 4;

  int L = blockIdx.x + blockIdx.y * NT;
  int L2 = (L & 7) * 420 + (L >> 3);
  const int bh = L2 / NT;
  const int tile = L2 - bh * NT;
  const int b = bh / H_, h = bh - b*H_;
  const int n0 = tile * TOUT;

  const bf16* Qp = Qb + (size_t)bh * (N_*D_);
  const bf16* Kp = Kb + (size_t)bh * (M_*D_);
  const bf16* Vp = Vt + (size_t)bh * (D_*M_);

  float wv[9];
#pragma unroll
  for (int q=0;q<9;q++) wv[q] = conv_w[h*9+q];
  const float cbv = conv_b[h];

  short8v qf[2][2];
#pragma unroll
  for (int rt=0;rt<2;rt++){
    int n = n0 - 1 + rt*16 + lr;
    bool ok = (unsigned)n < (unsigned)N_;
#pragma unroll
    for (int kk=0;kk<2;kk++){
      if (ok) qf[rt][kk] = *reinterpret_cast<const short8v*>(Qp + (size_t)n*D_ + kk*32 + g*8);
      else    qf[rt][kk] = short8v{0,0,0,0,0,0,0,0};
    }
  }

  f32x4 acc[8][2];
#pragma unroll
  for (int i=0;i<8;i++)
#pragma unroll
    for (int rt=0;rt<2;rt++)
      acc[i][rt] = (f32x4){0.f,0.f,0.f,0.f};

#pragma unroll
  for (int i=0;i<8;i++){
    const int m0 = (i*8 + w)*16;
    const bf16* kp = Kp + (size_t)(m0 + lr)*D_ + g*8;
    short8v kf0 = *reinterpret_cast<const short8v*>(kp);
    short8v kf1 = *reinterpret_cast<const short8v*>(kp + 32);
    acc[i][0] = __builtin_amdgcn_mfma_f32_16x16x32_bf16(qf[0][0], kf0, acc[i][0], 0,0,0);
    acc[i][1] = __builtin_amdgcn_mfma_f32_16x16x32_bf16(qf[1][0], kf0, acc[i][1], 0,0,0);
    acc[i][0] = __builtin_amdgcn_mfma_f32_16x16x32_bf16(qf[0][1], kf1, acc[i][0], 0,0,0);
    acc[i][1] = __builtin_amdgcn_mfma_f32_16x16x32_bf16(qf[1][1], kf1, acc[i][1], 0,0,0);
  }

  const float scale = 0.125f;
  float rmax[2][4], rsum[2][4];

#pragma unroll
  for (int rt=0;rt<2;rt++)
#pragma unroll
    for (int q=0;q<4;q++){
      float m = -1e30f;
#pragma unroll
      for (int i=0;i<8;i++) m = fmaxf(m, acc[i][rt][q]);
      m = fmaxf(m, __shfl_xor(m, 1));
      m = fmaxf(m, __shfl_xor(m, 2));
      m = fmaxf(m, __shfl_xor(m, 4));
      m = fmaxf(m, __shfl_xor(m, 8));
      rmax[rt][q] = m;
    }
  if (lr == 0){
#pragma unroll
    for (int rt=0;rt<2;rt++)
#pragma unroll
      for (int q=0;q<4;q++) red[0][w][rt*16+g*4+q] = rmax[rt][q];
  }
  __syncthreads();
#pragma unroll
  for (int rt=0;rt<2;rt++)
#pragma unroll
    for (int q=0;q<4;q++){
      int r = rt*16+g*4+q;
      float m = red[0][0][r];
#pragma unroll
      for (int ww=1;ww<8;ww++) m = fmaxf(m, red[0][ww][r]);
      rmax[rt][q] = m;
    }

#pragma unroll
  for (int rt=0;rt<2;rt++)
#pragma unroll
    for (int q=0;q<4;q++){
      float s = 0.f;
#pragma unroll
      for (int i=0;i<8;i++){
        float p = __expf((acc[i][rt][q] - rmax[rt][q]) * scale);
        acc[i][rt][q] = p;
        s += p;
      }
      s += __shfl_xor(s, 1);
      s += __shfl_xor(s, 2);
      s += __shfl_xor(s, 4);
      s += __shfl_xor(s, 8);
      rsum[rt][q] = s;
    }
  if (lr == 0){
#pragma unroll
    for (int rt=0;rt<2;rt++)
#pragma unroll
      for (int q=0;q<4;q++) red[1][w][rt*16+g*4+q] = rsum[rt][q];
  }
  __syncthreads();

  float rinv[2][4];
#pragma unroll
  for (int rt=0;rt<2;rt++)
#pragma unroll
    for (int q=0;q<4;q++){
      int r = rt*16+g*4+q;
      float s = red[1][0][r];
#pragma unroll
      for (int ww=1;ww<8;ww++) s += red[1][ww][r];
      int n = n0 - 1 + r;
      rinv[rt][q] = ((unsigned)n < (unsigned)N_) ? (1.0f / s) : 0.f;
    }

#pragma unroll
  for (int i=0;i<8;i++){
    const int m = (i*8 + w)*16 + lr;
#pragma unroll
    for (int rt=0;rt<2;rt++){
      bf162* dp = reinterpret_cast<bf162*>(&smP[m*34 + rt*16 + g*4]);
      bf162 v0, v1;
      v0.x = f2bf(acc[i][rt][0] * rinv[rt][0]);
      v0.y = f2bf(acc[i][rt][1] * rinv[rt][1]);
      v1.x = f2bf(acc[i][rt][2] * rinv[rt][2]);
      v1.y = f2bf(acc[i][rt][3] * rinv[rt][3]);
      dp[0] = v0; dp[1] = v1;
    }
  }
  __syncthreads();

  const int mm = t & 127, rb = t >> 7;
  const int rtw = w >> 2, ctw = w & 3;
  const int rrow = rtw*16 + lr;
  f32x4 apv = (f32x4){0.f,0.f,0.f,0.f};

  for (int mc = 0; mc < M_; mc += 128){
    const int m = mc + mm;
    const int r0 = rb*8;
    float c0a[10], c1a[10], c2a[10];
#pragma unroll
    for (int q=0;q<10;q++){
      int rr = r0 - 1 + q;
      rr = rr < 0 ? 0 : (rr > 31 ? 31 : rr);
      c0a[q] = (m >= 1)      ? bf2f(smP[(m-1)*34 + rr]) : 0.f;
      c1a[q] =                 bf2f(smP[ m   *34 + rr]);
      c2a[q] = (m+1 < M_)    ? bf2f(smP[(m+1)*34 + rr]) : 0.f;
    }
#pragma unroll
    for (int q=0;q<8;q++){
      float v = cbv;
      v = fmaf(wv[0], c0a[q],   v); v = fmaf(wv[1], c1a[q],   v); v = fmaf(wv[2], c2a[q],   v);
      v = fmaf(wv[3], c0a[q+1], v); v = fmaf(wv[4], c1a[q+1], v); v = fmaf(wv[5], c2a[q+1], v);
      v = fmaf(wv[6], c0a[q+2], v); v = fmaf(wv[7], c1a[q+2], v); v = fmaf(wv[8], c2a[q+2], v);
      int r = r0 + q;
      Acs[r*128 + (mm ^ ((r & 7) << 3))] = f2bf(v);
    }
    __syncthreads();

#pragma unroll
    for (int ks=0;ks<4;ks++){
      short8v af = *reinterpret_cast<const short8v*>(
          &Acs[rrow*128 + ((ks*32 + g*8) ^ ((rrow & 7) << 3))]);
      short8v bfv = *reinterpret_cast<const short8v*>(
          Vp + (size_t)(ctw*16 + lr)*M_ + mc + ks*32 + g*8);
      apv = __builtin_amdgcn_mfma_f32_16x16x32_bf16(af, bfv, apv, 0,0,0);
    }
    __syncthreads();
  }

  const int dcol = ctw*16 + lr;
#pragma unroll
  for (int q=0;q<4;q++){
    int r = rtw*16 + g*4 + q;
    int n = n0 - 1 + r;
    if (r >= 1 && r <= 30 && n < N_){
      midb[((size_t)b*N_ + n)*C_ + h*D_ + dcol] = f2bf(apv[q]);
    }
  }
}

extern "C" void kernel_launch(void* const* d_in, const int* in_sizes, int n_in,
                              void* d_out, int out_size, void* d_ws, size_t ws_size,
                              hipStream_t stream) {
  const float* x     = (const float*)d_in[0];
  const float* ctx   = (const float*)d_in[1];
  const float* Wq    = (const float*)d_in[2];
  const float* Wkv   = (const float*)d_in[3];
  const float* convw = (const float*)d_in[4];
  const float* convb = (const float*)d_in[5];
  const float* Wp    = (const float*)d_in[6];
  const float* bp    = (const float*)d_in[7];
  float* out = (float*)d_out;

  char* ws = (char*)d_ws;
  bf16* buf0 = (bf16*)(ws);                  // 12582912 B (xb -> ctxb -> midb)
  bf16* Wqt  = (bf16*)(ws + 12582912);       // 1179648
  bf16* Wkvt = (bf16*)(ws + 13762560);       // 2359296
  bf16* Wpt  = (bf16*)(ws + 16121856);       // 1179648
  bf16* Qb   = (bf16*)(ws + 17301504);       // 12582912
  bf16* Kb   = (bf16*)(ws + 29884416);       // 12582912
  bf16* Vt   = (bf16*)(ws + 42467328);       // 12582912 -> end 55050240

  // weight transposes
  transpose_w<<<dim3(24,24), 256, 0, stream>>>(Wq,  Wqt,  768, 768);
  transpose_w<<<dim3(48,24), 256, 0, stream>>>(Wkv, Wkvt, 768, 1536);
  transpose_w<<<dim3(24,24), 256, 0, stream>>>(Wp,  Wpt,  768, 768);

  // Q = x @ Wq
  cvt_bf16<<<3072, 256, 0, stream>>>(x, buf0, 786432);
  gemm_bf16<<<384, 256, 0, stream>>>(buf0, Wqt, 768, 6, nullptr, nullptr, Qb, nullptr, nullptr, 0);
  // K,V = ctx @ Wkv
  cvt_bf16<<<3072, 256, 0, stream>>>(ctx, buf0, 786432);
  gemm_bf16<<<768, 256, 0, stream>>>(buf0, Wkvt, 768, 12, nullptr, nullptr, nullptr, Kb, Vt, 1);
  // fused attention -> midb (= buf0)
  attn_fused<<<dim3(NT,96), dim3(512), 0, stream>>>(Qb, Kb, Vt, convw, convb, buf0);
  // out = midb @ Wp + bp
  gemm_bf16<<<384, 256, 0, stream>>>(buf0, Wpt, 768, 6, bp, out, nullptr, nullptr, nullptr, 2);
}